// Round 15
// baseline (1792.556 us; speedup 1.0000x reference)
//
#include <hip/hip_runtime.h>

#define N_HID 128
typedef unsigned short u16;
typedef unsigned int u32;
typedef __attribute__((ext_vector_type(8))) short bfrag;   // 8 bf16 = 4 VGPR
typedef __attribute__((ext_vector_type(4))) float facc;    // 4 f32 acc

__device__ __forceinline__ float sigf(float x) { return 1.f / (1.f + __expf(-x)); }
__device__ __forceinline__ float tanh_fast(float x) { return 1.f - 2.f / (__expf(2.f * x) + 1.f); }
__device__ __forceinline__ u16 f2bf(float f) {
  u32 u = __float_as_uint(f);
  u += 0x7fffu + ((u >> 16) & 1u);
  return (u16)(u >> 16);
}
__device__ __forceinline__ float bf2f(u16 b) { return __uint_as_float(((u32)b) << 16); }

// ---------------------------------------------------------------------------
// WIH2[gc][k] = sum_c wih[gc][c] * W[c][k]   (fold edge-linear into GRU input weights)
__global__ __launch_bounds__(256) void wihw_kernel(const float* __restrict__ wih,
                                                   const float* __restrict__ W,
                                                   float* __restrict__ out) {
  int i = blockIdx.x * 256 + threadIdx.x;  // 384*128 = 49152
  if (i >= 49152) return;
  int gc = i >> 7, k = i & 127;
  float acc = 0.f;
  for (int c = 0; c < 128; c++) acc = fmaf(wih[gc * 128 + c], W[c * 128 + k], acc);
  out[i] = acc;
}

// wb[gc] = sum_c wih[gc][c] * b[c]  (deg-scaled bias term)
__global__ __launch_bounds__(256) void wb_kernel(const float* __restrict__ wih,
                                                 const float* __restrict__ b,
                                                 float* __restrict__ wb) {
  int gc = blockIdx.x * 256 + threadIdx.x;
  if (gc >= 384) return;
  float acc = 0.f;
  for (int c = 0; c < 128; c++) acc = fmaf(wih[gc * 128 + c], b[c], acc);
  wb[gc] = acc;
}

// packed per-channel epilogue constants:
// PB7[ch][8] = {biR+bhR, biZ+bhZ, biN, bhN, wbR, wbZ, wbN, 0}
__global__ __launch_bounds__(128) void pack_bias_kernel(const float* __restrict__ bih,
                                                        const float* __restrict__ bhh,
                                                        const float* __restrict__ wb,
                                                        float* __restrict__ PB7) {
  int ch = threadIdx.x;  // 128
  PB7[ch * 8 + 0] = bih[ch] + bhh[ch];
  PB7[ch * 8 + 1] = bih[128 + ch] + bhh[128 + ch];
  PB7[ch * 8 + 2] = bih[256 + ch];
  PB7[ch * 8 + 3] = bhh[256 + ch];
  PB7[ch * 8 + 4] = wb[ch];
  PB7[ch * 8 + 5] = wb[128 + ch];
  PB7[ch * 8 + 6] = wb[256 + ch];
  PB7[ch * 8 + 7] = 0.f;
}

// pack GRU weights. Packed col-tiles pct 0..31: cw=pct>>3, t=pct&7,
// kind=t>>1 (0=r,1=z,2=i_n,3=h_n), sub=t&1.
// PAIRED-CHANNEL mapping: ch = cw*32 + 2*(l&15) + sub.
// K axis = [s(0..127) | h(128..255)], k = kt*32+(l>>4)*8+e.
__global__ __launch_bounds__(256) void pack_gru_kernel(const float* __restrict__ wih,
                                                       const float* __restrict__ whh,
                                                       u16* __restrict__ GB) {
  int i = blockIdx.x * 256 + threadIdx.x;  // 8*32*64*8 = 131072
  if (i >= 131072) return;
  int e = i & 7, l = (i >> 3) & 63, pct = (i >> 9) & 31, kt = i >> 14;
  int cw = pct >> 3, t = pct & 7, kind = t >> 1, sub = t & 1;
  int ch = cw * 32 + ((l & 15) << 1) + sub;
  int k = kt * 32 + ((l >> 4) << 3) + e;
  float v = 0.f;
  if (kind == 0) v = (k < 128) ? wih[ch * 128 + k] : whh[ch * 128 + k - 128];
  else if (kind == 1) v = (k < 128) ? wih[(128 + ch) * 128 + k] : whh[(128 + ch) * 128 + k - 128];
  else if (kind == 2) v = (k < 128) ? wih[(256 + ch) * 128 + k] : 0.f;
  else v = (k >= 128) ? whh[(256 + ch) * 128 + k - 128] : 0.f;
  GB[i] = f2bf(v);
}

// ---------------------------------------------------------------------------
// pad features [n,64] -> hbf bf16 [n,128] (zero upper half)
__global__ __launch_bounds__(256) void pad_bf_kernel(const float* __restrict__ feat,
                                                     u16* __restrict__ hbf, int n) {
  int i = blockIdx.x * 256 + threadIdx.x;
  if (i >= n * 32) return;
  int node = i >> 5, c4 = i & 31;
  float4 v = make_float4(0.f, 0.f, 0.f, 0.f);
  if (c4 < 16) v = ((const float4*)feat)[(size_t)node * 16 + c4];
  u32 p0 = (u32)f2bf(v.x) | ((u32)f2bf(v.y) << 16);
  u32 p1 = (u32)f2bf(v.z) | ((u32)f2bf(v.w) << 16);
  ((uint2*)hbf)[i] = make_uint2(p0, p1);
}

// ---------------------------------------------------------------------------
// CSR build
__global__ __launch_bounds__(256) void hist_kernel(const int* __restrict__ dst,
                                                   int* __restrict__ deg, int E) {
  int e = blockIdx.x * 256 + threadIdx.x;
  if (e < E) atomicAdd(&deg[dst[e]], 1);
}

__global__ __launch_bounds__(256) void scan1_kernel(const int* __restrict__ deg,
                                                    int* __restrict__ out,
                                                    int* __restrict__ bsums, int n) {
  __shared__ int s[256];
  int t = threadIdx.x;
  int base = blockIdx.x * 4096 + t * 16;
  int v[16];
  int local = 0;
#pragma unroll
  for (int i = 0; i < 16; i++) {
    int x = (base + i < n) ? deg[base + i] : 0;
    v[i] = local;
    local += x;
  }
  s[t] = local;
  __syncthreads();
  for (int off = 1; off < 256; off <<= 1) {
    int add = (t >= off) ? s[t - off] : 0;
    __syncthreads();
    s[t] += add;
    __syncthreads();
  }
  int texcl = s[t] - local;
#pragma unroll
  for (int i = 0; i < 16; i++)
    if (base + i < n) out[base + i] = texcl + v[i];
  if (t == 255) bsums[blockIdx.x] = s[255];
}

__global__ __launch_bounds__(256) void scan_tops_kernel(int* __restrict__ bsums, int nb) {
  __shared__ int s[256];
  int t = threadIdx.x;
  int orig = (t < nb) ? bsums[t] : 0;
  s[t] = orig;
  __syncthreads();
  for (int off = 1; off < 256; off <<= 1) {
    int add = (t >= off) ? s[t - off] : 0;
    __syncthreads();
    s[t] += add;
    __syncthreads();
  }
  if (t < nb) bsums[t] = s[t] - orig;
}

__global__ __launch_bounds__(256) void scan_add_kernel(int* __restrict__ rowptr,
                                                       const int* __restrict__ bsums,
                                                       int n, int E) {
  int i = blockIdx.x * 256 + threadIdx.x;
  if (i < n) rowptr[i] += bsums[i / 4096];
  if (i == n) rowptr[n] = E;
}

// csr stores src*16 (uint4-index prescale) to shorten the gather address chain
__global__ __launch_bounds__(256) void bucket_kernel(const int* __restrict__ src,
                                                     const int* __restrict__ dst,
                                                     const int* __restrict__ rowptr,
                                                     int* __restrict__ cursor,
                                                     int* __restrict__ csr_src, int E) {
  int e = blockIdx.x * 256 + threadIdx.x;
  if (e >= E) return;
  int d = dst[e];
  int p = atomicAdd(&cursor[d], 1);
  csr_src[rowptr[d] + p] = src[e] * 16;
}
// NOTE: after bucket_kernel, cursor[] == degree[] again — reused as deg input to gru.

// ---------------------------------------------------------------------------
// degree-sort: histogram of clamped degree
__global__ __launch_bounds__(256) void deg_hist_kernel(const int* __restrict__ deg,
                                                       int* __restrict__ dhist, int n) {
  int i = blockIdx.x * 256 + threadIdx.x;
  if (i < n) atomicAdd(&dhist[min(deg[i], 255)], 1);
}

// scatter node ids into degree-sorted order (dhist holds exclusive bases; destroyed)
__global__ __launch_bounds__(256) void perm_scatter_kernel(const int* __restrict__ deg,
                                                           int* __restrict__ dbase,
                                                           int* __restrict__ perm, int n) {
  int i = blockIdx.x * 256 + threadIdx.x;
  if (i >= n) return;
  int d = min(deg[i], 255);
  int pos = atomicAdd(&dbase[d], 1);
  perm[pos] = i;
}

// ---------------------------------------------------------------------------
// Fused gather + GRU via MFMA, bf16 state, DEGREE-SORTED node assignment.
// Block processes 64 similar-degree nodes perm[base..base+64) -> no wave
// divergence in the gather trip counts. Block: 512 thr = 8 waves.
// Wave w: cw=w&3 -> channels cw*32..+31 (all gates); nh=w>>2 -> nodes nh*32..+31.
__global__ __launch_bounds__(512) void gru_fused_kernel(const u16* __restrict__ hbf_in,
                                                        u16* __restrict__ hbf_out,
                                                        const u16* __restrict__ GB,
                                                        const float* __restrict__ PB7,
                                                        const int* __restrict__ rowptr,
                                                        const int* __restrict__ csr_src,
                                                        const int* __restrict__ deg,
                                                        const int* __restrict__ perm, int n) {
  __shared__ __align__(16) u16 sX[64 * 256];  // 32 KB, XOR-swizzled
  __shared__ float sD[64];                     // per-node degree (f32)
  __shared__ int sP[64];                       // per-node global id (perm)
  const int tid = threadIdx.x;
  const int base = blockIdx.x * 64;

  // stage perm + deg for this block's nodes
  if (tid < 64) {
    int pidx = base + tid;
    if (pidx >= n) pidx = n - 1;
    int pn = perm[pidx];
    sP[tid] = pn;
    sD[tid] = (float)deg[pn];
  }
  __syncthreads();

  // Phase A: stage h rows into chunks 16..31 (1024 x 16B)
  for (int it = 0; it < 2; it++) {
    int cid = it * 512 + tid;
    int node = cid >> 4, cc = cid & 15;
    int pn = sP[node];
    uint4 v = ((const uint4*)hbf_in)[(size_t)pn * 16 + cc];
    int c = 16 + cc;
    *(uint4*)((char*)sX + node * 512 + ((c ^ (node & 7)) << 4)) = v;
  }

  // Phase B: gather neighbor sums into chunks 0..15.
  // 8 threads per node, 16 channels (2 x uint4 chunks) per thread, f32 accum.
  {
    int node = tid >> 3, p = tid & 7;
    int pn = sP[node];
    int beg = rowptr[pn], end = rowptr[pn + 1];
    float acc[16];
#pragma unroll
    for (int i = 0; i < 16; i++) acc[i] = 0.f;
#define ACC8(v, o)                                                       \
    acc[o + 0] += bf2f((u16)((v).x & 0xffff)); acc[o + 1] += bf2f((u16)((v).x >> 16)); \
    acc[o + 2] += bf2f((u16)((v).y & 0xffff)); acc[o + 3] += bf2f((u16)((v).y >> 16)); \
    acc[o + 4] += bf2f((u16)((v).z & 0xffff)); acc[o + 5] += bf2f((u16)((v).z >> 16)); \
    acc[o + 6] += bf2f((u16)((v).w & 0xffff)); acc[o + 7] += bf2f((u16)((v).w >> 16));
    const uint4* hp = (const uint4*)hbf_in + 2 * p;
    int j = beg;
    int nA = (j < end) ? csr_src[j] : 0;
    int nB = (j + 1 < end) ? csr_src[j + 1] : 0;
    for (; j + 1 < end; j += 2) {
      int o0 = nA, o1 = nB;
      nA = (j + 2 < end) ? csr_src[j + 2] : 0;
      nB = (j + 3 < end) ? csr_src[j + 3] : 0;
      uint4 a0 = hp[o0];
      uint4 a1 = hp[o0 + 1];
      uint4 b0 = hp[o1];
      uint4 b1 = hp[o1 + 1];
      ACC8(a0, 0); ACC8(a1, 8); ACC8(b0, 0); ACC8(b1, 8);
    }
    if (j < end) {
      int o0 = nA;
      uint4 a0 = hp[o0];
      uint4 a1 = hp[o0 + 1];
      ACC8(a0, 0); ACC8(a1, 8);
    }
#undef ACC8
    uint4 w0, w1;
    w0.x = (u32)f2bf(acc[0])  | ((u32)f2bf(acc[1])  << 16);
    w0.y = (u32)f2bf(acc[2])  | ((u32)f2bf(acc[3])  << 16);
    w0.z = (u32)f2bf(acc[4])  | ((u32)f2bf(acc[5])  << 16);
    w0.w = (u32)f2bf(acc[6])  | ((u32)f2bf(acc[7])  << 16);
    w1.x = (u32)f2bf(acc[8])  | ((u32)f2bf(acc[9])  << 16);
    w1.y = (u32)f2bf(acc[10]) | ((u32)f2bf(acc[11]) << 16);
    w1.z = (u32)f2bf(acc[12]) | ((u32)f2bf(acc[13]) << 16);
    w1.w = (u32)f2bf(acc[14]) | ((u32)f2bf(acc[15]) << 16);
    *(uint4*)((char*)sX + node * 512 + (((2 * p)     ^ (node & 7)) << 4)) = w0;
    *(uint4*)((char*)sX + node * 512 + (((2 * p + 1) ^ (node & 7)) << 4)) = w1;
  }
  __syncthreads();

  const int w = tid >> 6, l = tid & 63;
  const int cw = w & 3, nh = w >> 2;
  facc accR[2][2], accZ[2][2], accIN[2][2], accHN[2][2];
#pragma unroll
  for (int i = 0; i < 2; i++)
#pragma unroll
    for (int j = 0; j < 2; j++) {
      accR[i][j] = (facc)(0.f); accZ[i][j] = (facc)(0.f);
      accIN[i][j] = (facc)(0.f); accHN[i][j] = (facc)(0.f);
    }

#pragma unroll
  for (int kt = 0; kt < 8; kt++) {
    bfrag A[2];
#pragma unroll
    for (int rt = 0; rt < 2; rt++) {
      int row = nh * 32 + rt * 16 + (l & 15);
      int slot = kt * 4 + (l >> 4);
      A[rt] = *(const bfrag*)((const char*)sX + row * 512 + ((slot ^ (row & 7)) << 4));
    }
    const bfrag* gb = (const bfrag*)GB + (size_t)(kt * 32 + cw * 8) * 64 + l;
#pragma unroll
    for (int s2 = 0; s2 < 2; s2++) {
      bfrag Br = gb[s2 * 64];
      bfrag Bz = gb[(2 + s2) * 64];
#pragma unroll
      for (int rt = 0; rt < 2; rt++) {
        accR[rt][s2] = __builtin_amdgcn_mfma_f32_16x16x32_bf16(A[rt], Br, accR[rt][s2], 0, 0, 0);
        accZ[rt][s2] = __builtin_amdgcn_mfma_f32_16x16x32_bf16(A[rt], Bz, accZ[rt][s2], 0, 0, 0);
      }
    }
    if (kt < 4) {
#pragma unroll
      for (int s2 = 0; s2 < 2; s2++) {
        bfrag Bi = gb[(4 + s2) * 64];
#pragma unroll
        for (int rt = 0; rt < 2; rt++)
          accIN[rt][s2] = __builtin_amdgcn_mfma_f32_16x16x32_bf16(A[rt], Bi, accIN[rt][s2], 0, 0, 0);
      }
    } else {
#pragma unroll
      for (int s2 = 0; s2 < 2; s2++) {
        bfrag Bh = gb[(6 + s2) * 64];
#pragma unroll
        for (int rt = 0; rt < 2; rt++)
          accHN[rt][s2] = __builtin_amdgcn_mfma_f32_16x16x32_bf16(A[rt], Bh, accHN[rt][s2], 0, 0, 0);
      }
    }
  }

  // epilogue: all inputs on-chip; store via perm (duplicates in tail write same value)
  {
    int m = l & 15;
    int ch0 = cw * 32 + (m << 1);
    const float4* pb = (const float4*)(PB7 + ch0 * 8);
    float4 c0a = pb[0], c0b = pb[1];  // ch0:   {BR, BZ, biN, bhN} {wbR, wbZ, wbN, -}
    float4 c1a = pb[2], c1b = pb[3];  // ch0+1
    int hc = 16 + (ch0 >> 3);         // h chunk index
    int hb = (ch0 & 7) * 2;           // byte offset within chunk (4B-aligned)
#pragma unroll
    for (int rt = 0; rt < 2; rt++)
#pragma unroll
      for (int j = 0; j < 4; j++) {
        int gl = nh * 32 + rt * 16 + ((l >> 4) << 2) + j;
        float dg = sD[gl];
        u32 hop = *(const u32*)((const char*)sX + gl * 512 + ((hc ^ (gl & 7)) << 4) + hb);
        float ho0 = bf2f((u16)(hop & 0xffff));
        float ho1 = bf2f((u16)(hop >> 16));
        float r0 = sigf(accR[rt][0][j] + dg * c0b.x + c0a.x);
        float z0 = sigf(accZ[rt][0][j] + dg * c0b.y + c0a.y);
        float nn0 = tanh_fast(accIN[rt][0][j] + dg * c0b.z + c0a.z + r0 * (accHN[rt][0][j] + c0a.w));
        float hn0 = (1.f - z0) * nn0 + z0 * ho0;
        float r1 = sigf(accR[rt][1][j] + dg * c1b.x + c1a.x);
        float z1 = sigf(accZ[rt][1][j] + dg * c1b.y + c1a.y);
        float nn1 = tanh_fast(accIN[rt][1][j] + dg * c1b.z + c1a.z + r1 * (accHN[rt][1][j] + c1a.w));
        float hn1 = (1.f - z1) * nn1 + z1 * ho1;
        *(u32*)&hbf_out[(size_t)sP[gl] * 128 + ch0] = (u32)f2bf(hn0) | ((u32)f2bf(hn1) << 16);
      }
  }
}

// ---------------------------------------------------------------------------
// out = bf16 h @ fc_w^T + fc_b -> [n,2]; one wave per node, shuffle reduce
__global__ __launch_bounds__(256) void head_kernel(const u16* __restrict__ hbf,
                                                   const float* __restrict__ fc_w,
                                                   const float* __restrict__ fc_b,
                                                   float* __restrict__ out, int n) {
  int wave = (blockIdx.x * 256 + threadIdx.x) >> 6;
  int lane = threadIdx.x & 63;
  if (wave >= n) return;
  u32 hv = ((const u32*)hbf)[(size_t)wave * 64 + lane];
  float h0 = bf2f((u16)(hv & 0xffff)), h1 = bf2f((u16)(hv >> 16));
  float2 w0 = ((const float2*)fc_w)[lane];
  float2 w1 = ((const float2*)fc_w)[64 + lane];
  float p0 = h0 * w0.x + h1 * w0.y;
  float p1 = h0 * w1.x + h1 * w1.y;
#pragma unroll
  for (int off = 32; off > 0; off >>= 1) {
    p0 += __shfl_down(p0, off, 64);
    p1 += __shfl_down(p1, off, 64);
  }
  if (lane == 0) {
    out[(size_t)wave * 2 + 0] = p0 + fc_b[0];
    out[(size_t)wave * 2 + 1] = p1 + fc_b[1];
  }
}

// ---------------------------------------------------------------------------
extern "C" void kernel_launch(void* const* d_in, const int* in_sizes, int n_in,
                              void* d_out, int out_size, void* d_ws, size_t ws_size,
                              hipStream_t stream) {
  const float* feat = (const float*)d_in[0];
  const int* src = (const int*)d_in[1];
  const int* dst = (const int*)d_in[2];
  const int N = in_sizes[0] / 64;
  const int E = in_sizes[1];

  const float* Wl[2]  = {(const float*)d_in[3], (const float*)d_in[9]};
  const float* bl[2]  = {(const float*)d_in[4], (const float*)d_in[10]};
  const float* wih[2] = {(const float*)d_in[5], (const float*)d_in[11]};
  const float* whh[2] = {(const float*)d_in[6], (const float*)d_in[12]};
  const float* bih[2] = {(const float*)d_in[7], (const float*)d_in[13]};
  const float* bhh[2] = {(const float*)d_in[8], (const float*)d_in[14]};
  const float* fcw = (const float*)d_in[15];
  const float* fcb = (const float*)d_in[16];

  // workspace layout (16B-aligned by construction)
  u16* hbf0 = (u16*)d_ws;                        // N*128 bf16 (double buffer A)
  u16* hbf1 = hbf0 + (size_t)N * 128;            // N*128 bf16 (double buffer B)
  float* WIH2[2];
  WIH2[0] = (float*)(hbf1 + (size_t)N * 128);
  WIH2[1] = WIH2[0] + 49152;
  float* wb2[2] = {WIH2[1] + 49152, WIH2[1] + 49152 + 384};
  u16* GB[2];
  GB[0] = (u16*)(wb2[1] + 384);
  GB[1] = GB[0] + 131072;
  float* PB7[2];
  PB7[0] = (float*)(GB[1] + 131072);             // 128*8 f32 each
  PB7[1] = PB7[0] + 1024;
  int* rowptr = (int*)(PB7[1] + 1024);           // N+1
  int* deg = rowptr + (N + 1);                   // cursor during bucket; ends as degree
  int* csr_src = deg + N;
  int* bsums = csr_src + E;                      // 256
  int* dhist = bsums + 256;                      // 256
  int* perm = dhist + 256;                       // N

  // --- one-time: weight fold+pack + pad + CSR build + degree sort ---
  for (int l = 0; l < 2; l++) {
    wihw_kernel<<<192, 256, 0, stream>>>(wih[l], Wl[l], WIH2[l]);
    wb_kernel<<<2, 256, 0, stream>>>(wih[l], bl[l], wb2[l]);
    pack_gru_kernel<<<512, 256, 0, stream>>>(WIH2[l], whh[l], GB[l]);
    pack_bias_kernel<<<1, 128, 0, stream>>>(bih[l], bhh[l], wb2[l], PB7[l]);
  }
  pad_bf_kernel<<<(N * 32 + 255) / 256, 256, 0, stream>>>(feat, hbf0, N);

  int nb = (N + 4095) / 4096;
  hipMemsetAsync(deg, 0, (size_t)N * sizeof(int), stream);
  hist_kernel<<<(E + 255) / 256, 256, 0, stream>>>(dst, deg, E);
  scan1_kernel<<<nb, 256, 0, stream>>>(deg, rowptr, bsums, N);
  scan_tops_kernel<<<1, 256, 0, stream>>>(bsums, nb);
  scan_add_kernel<<<(N + 256) / 256, 256, 0, stream>>>(rowptr, bsums, N, E);
  hipMemsetAsync(deg, 0, (size_t)N * sizeof(int), stream);
  bucket_kernel<<<(E + 255) / 256, 256, 0, stream>>>(src, dst, rowptr, deg, csr_src, E);

  // degree sort: hist -> exclusive scan (reuse scan_tops) -> scatter
  hipMemsetAsync(dhist, 0, 256 * sizeof(int), stream);
  deg_hist_kernel<<<(N + 255) / 256, 256, 0, stream>>>(deg, dhist, N);
  scan_tops_kernel<<<1, 256, 0, stream>>>(dhist, 256);
  perm_scatter_kernel<<<(N + 255) / 256, 256, 0, stream>>>(deg, dhist, perm, N);

  // --- main loop: one fused dispatch per step ---
  u16* hb[2] = {hbf0, hbf1};
  int cur = 0;
  int nblk = (N + 63) / 64;
  for (int layer = 0; layer < 2; layer++) {
    for (int step = 0; step < 5; step++) {
      gru_fused_kernel<<<nblk, 512, 0, stream>>>(hb[cur], hb[cur ^ 1], GB[layer], PB7[layer],
                                                 rowptr, csr_src, deg, perm, N);
      cur ^= 1;
    }
  }

  head_kernel<<<(N + 3) / 4, 256, 0, stream>>>(hb[cur], fcw, fcb, (float*)d_out, N);
}

// Round 16
// 873.868 us; speedup vs baseline: 2.0513x; 2.0513x over previous
//
#include <hip/hip_runtime.h>

#define N_HID 128
typedef unsigned short u16;
typedef unsigned int u32;
typedef __attribute__((ext_vector_type(8))) short bfrag;   // 8 bf16 = 4 VGPR
typedef __attribute__((ext_vector_type(4))) float facc;    // 4 f32 acc

__device__ __forceinline__ float sigf(float x) { return 1.f / (1.f + __expf(-x)); }
__device__ __forceinline__ float tanh_fast(float x) { return 1.f - 2.f / (__expf(2.f * x) + 1.f); }
__device__ __forceinline__ u16 f2bf(float f) {
  u32 u = __float_as_uint(f);
  u += 0x7fffu + ((u >> 16) & 1u);
  return (u16)(u >> 16);
}
__device__ __forceinline__ float bf2f(u16 b) { return __uint_as_float(((u32)b) << 16); }

// ---------------------------------------------------------------------------
// WIH2[gc][k] = sum_c wih[gc][c] * W[c][k]   (fold edge-linear into GRU input weights)
__global__ __launch_bounds__(256) void wihw_kernel(const float* __restrict__ wih,
                                                   const float* __restrict__ W,
                                                   float* __restrict__ out) {
  int i = blockIdx.x * 256 + threadIdx.x;  // 384*128 = 49152
  if (i >= 49152) return;
  int gc = i >> 7, k = i & 127;
  float acc = 0.f;
  for (int c = 0; c < 128; c++) acc = fmaf(wih[gc * 128 + c], W[c * 128 + k], acc);
  out[i] = acc;
}

// wb[gc] = sum_c wih[gc][c] * b[c]  (deg-scaled bias term)
__global__ __launch_bounds__(256) void wb_kernel(const float* __restrict__ wih,
                                                 const float* __restrict__ b,
                                                 float* __restrict__ wb) {
  int gc = blockIdx.x * 256 + threadIdx.x;
  if (gc >= 384) return;
  float acc = 0.f;
  for (int c = 0; c < 128; c++) acc = fmaf(wih[gc * 128 + c], b[c], acc);
  wb[gc] = acc;
}

// packed per-channel epilogue constants:
// PB7[ch][8] = {biR+bhR, biZ+bhZ, biN, bhN, wbR, wbZ, wbN, 0}
__global__ __launch_bounds__(128) void pack_bias_kernel(const float* __restrict__ bih,
                                                        const float* __restrict__ bhh,
                                                        const float* __restrict__ wb,
                                                        float* __restrict__ PB7) {
  int ch = threadIdx.x;  // 128
  PB7[ch * 8 + 0] = bih[ch] + bhh[ch];
  PB7[ch * 8 + 1] = bih[128 + ch] + bhh[128 + ch];
  PB7[ch * 8 + 2] = bih[256 + ch];
  PB7[ch * 8 + 3] = bhh[256 + ch];
  PB7[ch * 8 + 4] = wb[ch];
  PB7[ch * 8 + 5] = wb[128 + ch];
  PB7[ch * 8 + 6] = wb[256 + ch];
  PB7[ch * 8 + 7] = 0.f;
}

// pack GRU weights. Packed col-tiles pct 0..31: cw=pct>>3, t=pct&7,
// kind=t>>1 (0=r,1=z,2=i_n,3=h_n), sub=t&1.
// PAIRED-CHANNEL mapping: ch = cw*32 + 2*(l&15) + sub.
// K axis = [s(0..127) | h(128..255)], k = kt*32+(l>>4)*8+e.
__global__ __launch_bounds__(256) void pack_gru_kernel(const float* __restrict__ wih,
                                                       const float* __restrict__ whh,
                                                       u16* __restrict__ GB) {
  int i = blockIdx.x * 256 + threadIdx.x;  // 8*32*64*8 = 131072
  if (i >= 131072) return;
  int e = i & 7, l = (i >> 3) & 63, pct = (i >> 9) & 31, kt = i >> 14;
  int cw = pct >> 3, t = pct & 7, kind = t >> 1, sub = t & 1;
  int ch = cw * 32 + ((l & 15) << 1) + sub;
  int k = kt * 32 + ((l >> 4) << 3) + e;
  float v = 0.f;
  if (kind == 0) v = (k < 128) ? wih[ch * 128 + k] : whh[ch * 128 + k - 128];
  else if (kind == 1) v = (k < 128) ? wih[(128 + ch) * 128 + k] : whh[(128 + ch) * 128 + k - 128];
  else if (kind == 2) v = (k < 128) ? wih[(256 + ch) * 128 + k] : 0.f;
  else v = (k >= 128) ? whh[(256 + ch) * 128 + k - 128] : 0.f;
  GB[i] = f2bf(v);
}

// ---------------------------------------------------------------------------
// pad features [n,64] -> hbf bf16 [n,128] (zero upper half)
__global__ __launch_bounds__(256) void pad_bf_kernel(const float* __restrict__ feat,
                                                     u16* __restrict__ hbf, int n) {
  int i = blockIdx.x * 256 + threadIdx.x;
  if (i >= n * 32) return;
  int node = i >> 5, c4 = i & 31;
  float4 v = make_float4(0.f, 0.f, 0.f, 0.f);
  if (c4 < 16) v = ((const float4*)feat)[(size_t)node * 16 + c4];
  u32 p0 = (u32)f2bf(v.x) | ((u32)f2bf(v.y) << 16);
  u32 p1 = (u32)f2bf(v.z) | ((u32)f2bf(v.w) << 16);
  ((uint2*)hbf)[i] = make_uint2(p0, p1);
}

// ---------------------------------------------------------------------------
// CSR build
__global__ __launch_bounds__(256) void hist_kernel(const int* __restrict__ dst,
                                                   int* __restrict__ deg, int E) {
  int e = blockIdx.x * 256 + threadIdx.x;
  if (e < E) atomicAdd(&deg[dst[e]], 1);
}

__global__ __launch_bounds__(256) void scan1_kernel(const int* __restrict__ deg,
                                                    int* __restrict__ out,
                                                    int* __restrict__ bsums, int n) {
  __shared__ int s[256];
  int t = threadIdx.x;
  int base = blockIdx.x * 4096 + t * 16;
  int v[16];
  int local = 0;
#pragma unroll
  for (int i = 0; i < 16; i++) {
    int x = (base + i < n) ? deg[base + i] : 0;
    v[i] = local;
    local += x;
  }
  s[t] = local;
  __syncthreads();
  for (int off = 1; off < 256; off <<= 1) {
    int add = (t >= off) ? s[t - off] : 0;
    __syncthreads();
    s[t] += add;
    __syncthreads();
  }
  int texcl = s[t] - local;
#pragma unroll
  for (int i = 0; i < 16; i++)
    if (base + i < n) out[base + i] = texcl + v[i];
  if (t == 255) bsums[blockIdx.x] = s[255];
}

__global__ __launch_bounds__(256) void scan_tops_kernel(int* __restrict__ bsums, int nb) {
  __shared__ int s[256];
  int t = threadIdx.x;
  int orig = (t < nb) ? bsums[t] : 0;
  s[t] = orig;
  __syncthreads();
  for (int off = 1; off < 256; off <<= 1) {
    int add = (t >= off) ? s[t - off] : 0;
    __syncthreads();
    s[t] += add;
    __syncthreads();
  }
  if (t < nb) bsums[t] = s[t] - orig;
}

__global__ __launch_bounds__(256) void scan_add_kernel(int* __restrict__ rowptr,
                                                       const int* __restrict__ bsums,
                                                       int n, int E) {
  int i = blockIdx.x * 256 + threadIdx.x;
  if (i < n) rowptr[i] += bsums[i / 4096];
  if (i == n) rowptr[n] = E;
}

// csr stores src*16 (uint4-index prescale) to shorten the gather address chain
__global__ __launch_bounds__(256) void bucket_kernel(const int* __restrict__ src,
                                                     const int* __restrict__ dst,
                                                     const int* __restrict__ rowptr,
                                                     int* __restrict__ cursor,
                                                     int* __restrict__ csr_src, int E) {
  int e = blockIdx.x * 256 + threadIdx.x;
  if (e >= E) return;
  int d = dst[e];
  int p = atomicAdd(&cursor[d], 1);
  csr_src[rowptr[d] + p] = src[e] * 16;
}
// NOTE: after bucket_kernel, cursor[] == degree[] again — reused as deg input to gru.

// ---------------------------------------------------------------------------
// Fused gather + GRU via MFMA, bf16 state. X = [s_bf | h_bf] (K=256), gathered
// in-kernel. Block: 512 thr = 8 waves, 64 nodes (2 blocks/CU -> phase overlap).
// Wave w: cw=w&3 -> channels cw*32..+31 (all gates); nh=w>>2 -> nodes nh*32..+31.
// Epilogue: h_old from LDS X-tile, deg from LDS, biases from packed PB7.
// T5: setprio(1) around the MFMA cluster — pays with 2 blocks/CU at different
// phases (gather waves vs MFMA waves), per learn_hip m191 mechanism.
__global__ __launch_bounds__(512) void gru_fused_kernel(const u16* __restrict__ hbf_in,
                                                        u16* __restrict__ hbf_out,
                                                        const u16* __restrict__ GB,
                                                        const float* __restrict__ PB7,
                                                        const int* __restrict__ rowptr,
                                                        const int* __restrict__ csr_src,
                                                        const int* __restrict__ deg, int n) {
  __shared__ __align__(16) u16 sX[64 * 256];  // 32 KB, XOR-swizzled
  __shared__ float sD[64];                     // per-node degree (f32)
  const int tid = threadIdx.x;
  const int base = blockIdx.x * 64;

  // Phase A: stage h rows into chunks 16..31 (1024 x 16B) + deg -> sD
  if (tid < 64) {
    int gn = base + tid;
    if (gn >= n) gn = n - 1;
    sD[tid] = (float)deg[gn];
  }
  for (int it = 0; it < 2; it++) {
    int cid = it * 512 + tid;
    int node = cid >> 4, cc = cid & 15;
    int gn = base + node;
    if (gn >= n) gn = n - 1;
    uint4 v = ((const uint4*)hbf_in)[(size_t)gn * 16 + cc];
    int c = 16 + cc;
    *(uint4*)((char*)sX + node * 512 + ((c ^ (node & 7)) << 4)) = v;
  }

  // Phase B: gather neighbor sums into chunks 0..15.
  // 8 threads per node, 16 channels (2 x uint4 chunks) per thread, f32 accum.
  {
    int node = tid >> 3, p = tid & 7;
    int gn = base + node;
    if (gn >= n) gn = n - 1;
    int beg = rowptr[gn], end = rowptr[gn + 1];
    float acc[16];
#pragma unroll
    for (int i = 0; i < 16; i++) acc[i] = 0.f;
#define ACC8(v, o)                                                       \
    acc[o + 0] += bf2f((u16)((v).x & 0xffff)); acc[o + 1] += bf2f((u16)((v).x >> 16)); \
    acc[o + 2] += bf2f((u16)((v).y & 0xffff)); acc[o + 3] += bf2f((u16)((v).y >> 16)); \
    acc[o + 4] += bf2f((u16)((v).z & 0xffff)); acc[o + 5] += bf2f((u16)((v).z >> 16)); \
    acc[o + 6] += bf2f((u16)((v).w & 0xffff)); acc[o + 7] += bf2f((u16)((v).w >> 16));
    const uint4* hp = (const uint4*)hbf_in + 2 * p;
    int j = beg;
    int nA = (j < end) ? csr_src[j] : 0;
    int nB = (j + 1 < end) ? csr_src[j + 1] : 0;
    for (; j + 1 < end; j += 2) {
      int o0 = nA, o1 = nB;
      nA = (j + 2 < end) ? csr_src[j + 2] : 0;
      nB = (j + 3 < end) ? csr_src[j + 3] : 0;
      uint4 a0 = hp[o0];
      uint4 a1 = hp[o0 + 1];
      uint4 b0 = hp[o1];
      uint4 b1 = hp[o1 + 1];
      ACC8(a0, 0); ACC8(a1, 8); ACC8(b0, 0); ACC8(b1, 8);
    }
    if (j < end) {
      int o0 = nA;
      uint4 a0 = hp[o0];
      uint4 a1 = hp[o0 + 1];
      ACC8(a0, 0); ACC8(a1, 8);
    }
#undef ACC8
    uint4 w0, w1;
    w0.x = (u32)f2bf(acc[0])  | ((u32)f2bf(acc[1])  << 16);
    w0.y = (u32)f2bf(acc[2])  | ((u32)f2bf(acc[3])  << 16);
    w0.z = (u32)f2bf(acc[4])  | ((u32)f2bf(acc[5])  << 16);
    w0.w = (u32)f2bf(acc[6])  | ((u32)f2bf(acc[7])  << 16);
    w1.x = (u32)f2bf(acc[8])  | ((u32)f2bf(acc[9])  << 16);
    w1.y = (u32)f2bf(acc[10]) | ((u32)f2bf(acc[11]) << 16);
    w1.z = (u32)f2bf(acc[12]) | ((u32)f2bf(acc[13]) << 16);
    w1.w = (u32)f2bf(acc[14]) | ((u32)f2bf(acc[15]) << 16);
    *(uint4*)((char*)sX + node * 512 + (((2 * p)     ^ (node & 7)) << 4)) = w0;
    *(uint4*)((char*)sX + node * 512 + (((2 * p + 1) ^ (node & 7)) << 4)) = w1;
  }
  __syncthreads();

  const int w = tid >> 6, l = tid & 63;
  const int cw = w & 3, nh = w >> 2;
  facc accR[2][2], accZ[2][2], accIN[2][2], accHN[2][2];
#pragma unroll
  for (int i = 0; i < 2; i++)
#pragma unroll
    for (int j = 0; j < 2; j++) {
      accR[i][j] = (facc)(0.f); accZ[i][j] = (facc)(0.f);
      accIN[i][j] = (facc)(0.f); accHN[i][j] = (facc)(0.f);
    }

  __builtin_amdgcn_s_setprio(1);
#pragma unroll
  for (int kt = 0; kt < 8; kt++) {
    bfrag A[2];
#pragma unroll
    for (int rt = 0; rt < 2; rt++) {
      int row = nh * 32 + rt * 16 + (l & 15);
      int slot = kt * 4 + (l >> 4);
      A[rt] = *(const bfrag*)((const char*)sX + row * 512 + ((slot ^ (row & 7)) << 4));
    }
    const bfrag* gb = (const bfrag*)GB + (size_t)(kt * 32 + cw * 8) * 64 + l;
#pragma unroll
    for (int s2 = 0; s2 < 2; s2++) {
      bfrag Br = gb[s2 * 64];
      bfrag Bz = gb[(2 + s2) * 64];
#pragma unroll
      for (int rt = 0; rt < 2; rt++) {
        accR[rt][s2] = __builtin_amdgcn_mfma_f32_16x16x32_bf16(A[rt], Br, accR[rt][s2], 0, 0, 0);
        accZ[rt][s2] = __builtin_amdgcn_mfma_f32_16x16x32_bf16(A[rt], Bz, accZ[rt][s2], 0, 0, 0);
      }
    }
    if (kt < 4) {
#pragma unroll
      for (int s2 = 0; s2 < 2; s2++) {
        bfrag Bi = gb[(4 + s2) * 64];
#pragma unroll
        for (int rt = 0; rt < 2; rt++)
          accIN[rt][s2] = __builtin_amdgcn_mfma_f32_16x16x32_bf16(A[rt], Bi, accIN[rt][s2], 0, 0, 0);
      }
    } else {
#pragma unroll
      for (int s2 = 0; s2 < 2; s2++) {
        bfrag Bh = gb[(6 + s2) * 64];
#pragma unroll
        for (int rt = 0; rt < 2; rt++)
          accHN[rt][s2] = __builtin_amdgcn_mfma_f32_16x16x32_bf16(A[rt], Bh, accHN[rt][s2], 0, 0, 0);
      }
    }
  }
  __builtin_amdgcn_s_setprio(0);

  // epilogue: all inputs on-chip (sX h-part intact: nothing wrote it post-stage)
  {
    int m = l & 15;
    int ch0 = cw * 32 + (m << 1);
    const float4* pb = (const float4*)(PB7 + ch0 * 8);
    float4 c0a = pb[0], c0b = pb[1];  // ch0:   {BR, BZ, biN, bhN} {wbR, wbZ, wbN, -}
    float4 c1a = pb[2], c1b = pb[3];  // ch0+1
    int hc = 16 + (ch0 >> 3);         // h chunk index
    int hb = (ch0 & 7) * 2;           // byte offset within chunk (4B-aligned)
#pragma unroll
    for (int rt = 0; rt < 2; rt++)
#pragma unroll
      for (int j = 0; j < 4; j++) {
        int gl = nh * 32 + rt * 16 + ((l >> 4) << 2) + j;
        int g = base + gl;
        float dg = sD[gl];
        u32 hop = *(const u32*)((const char*)sX + gl * 512 + ((hc ^ (gl & 7)) << 4) + hb);
        float ho0 = bf2f((u16)(hop & 0xffff));
        float ho1 = bf2f((u16)(hop >> 16));
        float r0 = sigf(accR[rt][0][j] + dg * c0b.x + c0a.x);
        float z0 = sigf(accZ[rt][0][j] + dg * c0b.y + c0a.y);
        float nn0 = tanh_fast(accIN[rt][0][j] + dg * c0b.z + c0a.z + r0 * (accHN[rt][0][j] + c0a.w));
        float hn0 = (1.f - z0) * nn0 + z0 * ho0;
        float r1 = sigf(accR[rt][1][j] + dg * c1b.x + c1a.x);
        float z1 = sigf(accZ[rt][1][j] + dg * c1b.y + c1a.y);
        float nn1 = tanh_fast(accIN[rt][1][j] + dg * c1b.z + c1a.z + r1 * (accHN[rt][1][j] + c1a.w));
        float hn1 = (1.f - z1) * nn1 + z1 * ho1;
        if (g < n)
          *(u32*)&hbf_out[(size_t)g * 128 + ch0] = (u32)f2bf(hn0) | ((u32)f2bf(hn1) << 16);
      }
  }
}

// ---------------------------------------------------------------------------
// out = bf16 h @ fc_w^T + fc_b -> [n,2]; one wave per node, shuffle reduce
__global__ __launch_bounds__(256) void head_kernel(const u16* __restrict__ hbf,
                                                   const float* __restrict__ fc_w,
                                                   const float* __restrict__ fc_b,
                                                   float* __restrict__ out, int n) {
  int wave = (blockIdx.x * 256 + threadIdx.x) >> 6;
  int lane = threadIdx.x & 63;
  if (wave >= n) return;
  u32 hv = ((const u32*)hbf)[(size_t)wave * 64 + lane];
  float h0 = bf2f((u16)(hv & 0xffff)), h1 = bf2f((u16)(hv >> 16));
  float2 w0 = ((const float2*)fc_w)[lane];
  float2 w1 = ((const float2*)fc_w)[64 + lane];
  float p0 = h0 * w0.x + h1 * w0.y;
  float p1 = h0 * w1.x + h1 * w1.y;
#pragma unroll
  for (int off = 32; off > 0; off >>= 1) {
    p0 += __shfl_down(p0, off, 64);
    p1 += __shfl_down(p1, off, 64);
  }
  if (lane == 0) {
    out[(size_t)wave * 2 + 0] = p0 + fc_b[0];
    out[(size_t)wave * 2 + 1] = p1 + fc_b[1];
  }
}

// ---------------------------------------------------------------------------
extern "C" void kernel_launch(void* const* d_in, const int* in_sizes, int n_in,
                              void* d_out, int out_size, void* d_ws, size_t ws_size,
                              hipStream_t stream) {
  const float* feat = (const float*)d_in[0];
  const int* src = (const int*)d_in[1];
  const int* dst = (const int*)d_in[2];
  const int N = in_sizes[0] / 64;
  const int E = in_sizes[1];

  const float* Wl[2]  = {(const float*)d_in[3], (const float*)d_in[9]};
  const float* bl[2]  = {(const float*)d_in[4], (const float*)d_in[10]};
  const float* wih[2] = {(const float*)d_in[5], (const float*)d_in[11]};
  const float* whh[2] = {(const float*)d_in[6], (const float*)d_in[12]};
  const float* bih[2] = {(const float*)d_in[7], (const float*)d_in[13]};
  const float* bhh[2] = {(const float*)d_in[8], (const float*)d_in[14]};
  const float* fcw = (const float*)d_in[15];
  const float* fcb = (const float*)d_in[16];

  // workspace layout (16B-aligned by construction)
  u16* hbf0 = (u16*)d_ws;                        // N*128 bf16 (double buffer A)
  u16* hbf1 = hbf0 + (size_t)N * 128;            // N*128 bf16 (double buffer B)
  float* WIH2[2];
  WIH2[0] = (float*)(hbf1 + (size_t)N * 128);
  WIH2[1] = WIH2[0] + 49152;
  float* wb2[2] = {WIH2[1] + 49152, WIH2[1] + 49152 + 384};
  u16* GB[2];
  GB[0] = (u16*)(wb2[1] + 384);
  GB[1] = GB[0] + 131072;
  float* PB7[2];
  PB7[0] = (float*)(GB[1] + 131072);             // 128*8 f32 each
  PB7[1] = PB7[0] + 1024;
  int* rowptr = (int*)(PB7[1] + 1024);           // N+1
  int* deg = rowptr + (N + 1);                   // cursor during bucket; ends as degree
  int* csr_src = deg + N;
  int* bsums = csr_src + E;

  // --- one-time: weight fold+pack + pad + CSR build ---
  for (int l = 0; l < 2; l++) {
    wihw_kernel<<<192, 256, 0, stream>>>(wih[l], Wl[l], WIH2[l]);
    wb_kernel<<<2, 256, 0, stream>>>(wih[l], bl[l], wb2[l]);
    pack_gru_kernel<<<512, 256, 0, stream>>>(WIH2[l], whh[l], GB[l]);
    pack_bias_kernel<<<1, 128, 0, stream>>>(bih[l], bhh[l], wb2[l], PB7[l]);
  }
  pad_bf_kernel<<<(N * 32 + 255) / 256, 256, 0, stream>>>(feat, hbf0, N);

  int nb = (N + 4095) / 4096;
  hipMemsetAsync(deg, 0, (size_t)N * sizeof(int), stream);
  hist_kernel<<<(E + 255) / 256, 256, 0, stream>>>(dst, deg, E);
  scan1_kernel<<<nb, 256, 0, stream>>>(deg, rowptr, bsums, N);
  scan_tops_kernel<<<1, 256, 0, stream>>>(bsums, nb);
  scan_add_kernel<<<(N + 256) / 256, 256, 0, stream>>>(rowptr, bsums, N, E);
  hipMemsetAsync(deg, 0, (size_t)N * sizeof(int), stream);
  bucket_kernel<<<(E + 255) / 256, 256, 0, stream>>>(src, dst, rowptr, deg, csr_src, E);

  // --- main loop: one fused dispatch per step ---
  u16* hb[2] = {hbf0, hbf1};
  int cur = 0;
  int nblk = (N + 63) / 64;
  for (int layer = 0; layer < 2; layer++) {
    for (int step = 0; step < 5; step++) {
      gru_fused_kernel<<<nblk, 512, 0, stream>>>(hb[cur], hb[cur ^ 1], GB[layer], PB7[layer],
                                                 rowptr, csr_src, deg, N);
      cur ^= 1;
    }
  }

  head_kernel<<<(N + 3) / 4, 256, 0, stream>>>(hb[cur], fcw, fcb, (float*)d_out, N);
}